// Round 15
// baseline (128.226 us; speedup 1.0000x reference)
//
#include <hip/hip_runtime.h>
#include <math.h>

#define N_PIX 8192      // 2*64*64
#define D 64
#define HW 4096         // h*w
#define BSTRIDE 262144  // d*h*w
#define C1 14.4269504088896340736f   // 10 * log2(e); |dot| <= 1
#define NSEG 32
#define SEGCOLS 256
#define BC 256

typedef __attribute__((ext_vector_type(8))) short short8;   // 8 bf16 = 4 VGPR
typedef __attribute__((ext_vector_type(4))) float f32x4;

__device__ inline ushort f2bf(float x) {   // fp32 -> bf16 RNE
    uint u = __float_as_uint(x);
    return (ushort)((u + 0x7FFFu + ((u >> 16) & 1u)) >> 16);
}

// ---------- K2 (fused): normalize-in-block + MFMA sim + fixed-shift exp ----------
// block = 4 waves; rows 256/block (64/wave), cols 256/block staged in LDS.
// grid (32, 32) = 1024 blocks = 4/CU exactly. Zero mid-loop barriers.
// bx==by blocks also emit diag (free, from the MFMA acc).
__global__ __launch_bounds__(256, 4) void ksim(const float* __restrict__ z1,
                                               const float* __restrict__ z2,
                                               float* __restrict__ ps,
                                               float* __restrict__ diag,
                                               float* __restrict__ out) {
    __shared__ ushort lds[BC * D];   // 32KB: [col][slot16], chunk k at slot k^(col&7)
    int tid = threadIdx.x;
    int wave = tid >> 6, lane = tid & 63;
    int lrow = lane & 15;        // A-row / B-col within 16
    int lk = lane >> 4;          // k-chunk 0..3
    int bx = blockIdx.x, by = blockIdx.y;
    int rbase = bx * 256 + wave * 64;
    int jbase = by * SEGCOLS;
    if (bx == 0 && by == 0 && tid == 0) out[0] = 0.f;   // kfinal runs after ksim

    // ---- B stage: thread t normalizes col jbase+t -> swizzled LDS ----
    {
        int col = jbase + tid;
        int cb = col >> 12, cp = col & 4095;
        const float* bsrc = z2 + (size_t)cb * BSTRIDE + cp;
        float v[D];
        float ss = 0.f;
#pragma unroll
        for (int c = 0; c < D; ++c) { v[c] = bsrc[(size_t)c * HW]; ss = fmaf(v[c], v[c], ss); }
        float inv = 1.0f / fmaxf(sqrtf(ss), 1e-12f);
        uint w[32];
#pragma unroll
        for (int c2 = 0; c2 < 32; ++c2)
            w[c2] = (uint)f2bf(v[2 * c2] * inv) | ((uint)f2bf(v[2 * c2 + 1] * inv) << 16);
        uint* lb = (uint*)lds;
        int t7 = tid & 7;
#pragma unroll
        for (int s = 0; s < 8; ++s) {          // instr s: slot varies per lane -> 2-way max
            int slot = s ^ t7;
            *(uint4*)(lb + tid * 32 + slot * 4) =
                make_uint4(w[4 * s], w[4 * s + 1], w[4 * s + 2], w[4 * s + 3]);
        }
    }

    // ---- A stage: lane normalizes its 4 rows from raw z1 ----
    short8 a0[4], a1[4];
#pragma unroll
    for (int rt = 0; rt < 4; ++rt) {
        int row = rbase + rt * 16 + lrow;
        int rb = row >> 12, rp = row & 4095;
        const float* asrc = z1 + (size_t)rb * BSTRIDE + (size_t)(lk * 8) * HW + rp;
        float v0[8], v1[8];
        float ss = 0.f;
#pragma unroll
        for (int j = 0; j < 8; ++j) {
            v0[j] = asrc[(size_t)j * HW];
            v1[j] = asrc[(size_t)(32 + j) * HW];
        }
#pragma unroll
        for (int j = 0; j < 8; ++j) { ss = fmaf(v0[j], v0[j], ss); ss = fmaf(v1[j], v1[j], ss); }
        ss += __shfl_xor(ss, 16);            // combine the 4 lk lanes of this row
        ss += __shfl_xor(ss, 32);
        float inv = 1.0f / fmaxf(sqrtf(ss), 1e-12f);
        short8 t0, t1;
#pragma unroll
        for (int j = 0; j < 8; ++j) {
            t0[j] = (short)f2bf(v0[j] * inv);
            t1[j] = (short)f2bf(v1[j] * inv);
        }
        a0[rt] = t0;
        a1[rt] = t1;
    }

    float s[16];
#pragma unroll
    for (int i = 0; i < 16; ++i) s[i] = 0.f;

    __syncthreads();                         // B tile complete

    const char* bb = (const char*)lds;
    int sw = lrow & 7;
    bool dblk = (bx == by);
    int wct = wave * 4;
    f32x4 z = {0.f, 0.f, 0.f, 0.f};

#pragma unroll
    for (int ct = 0; ct < BC / 16; ++ct) {
        int rowoff = (ct * 16 + lrow) << 7;
        short8 blo = *(const short8*)(bb + rowoff + ((lk ^ sw) << 4));
        short8 bhi = *(const short8*)(bb + rowoff + (((4 + lk) ^ sw) << 4));
#pragma unroll
        for (int rt = 0; rt < 4; ++rt) {
            f32x4 acc = __builtin_amdgcn_mfma_f32_16x16x32_bf16(a0[rt], blo, z, 0, 0, 0);
            acc = __builtin_amdgcn_mfma_f32_16x16x32_bf16(a1[rt], bhi, acc, 0, 0, 0);
            if (dblk && ct == wct + rt && (lrow >> 2) == lk) {   // free diag capture
                int rr = lrow & 3;
                float dv = rr == 0 ? acc[0] : (rr == 1 ? acc[1] : (rr == 2 ? acc[2] : acc[3]));
                diag[rbase + rt * 16 + lrow] = dv;
            }
#pragma unroll
            for (int r = 0; r < 4; ++r)
                s[rt * 4 + r] += __builtin_amdgcn_exp2f(fmaf(acc[r], C1, -C1));
        }
    }

    // reduce over 16 lanes sharing lk (different cols, same rows)
#pragma unroll
    for (int off = 1; off <= 8; off <<= 1) {
#pragma unroll
        for (int i = 0; i < 16; ++i) s[i] += __shfl_xor(s[i], off);
    }
    if (lrow == 0) {
#pragma unroll
        for (int rt = 0; rt < 4; ++rt)
#pragma unroll
            for (int r = 0; r < 4; ++r)
                ps[(size_t)(rbase + rt * 16 + lk * 4 + r) * NSEG + by] = s[rt * 4 + r];
    }
}

// ---------- K3: combine partials + diag + mean via atomic ----------
__global__ __launch_bounds__(64) void kfinal(const float* __restrict__ ps,
                                             const float* __restrict__ diag,
                                             float* __restrict__ out) {
    int tid = threadIdx.x;
    int row = blockIdx.x * 64 + tid;

    const f32x4* pp = (const f32x4*)(ps + (size_t)row * NSEG);
    float s = 0.f;
#pragma unroll
    for (int q = 0; q < NSEG / 4; ++q) {
        f32x4 v = pp[q];
        s += (v[0] + v[1]) + (v[2] + v[3]);
    }
    float val = 10.0f + __logf(s) - 10.0f * diag[row];

#pragma unroll
    for (int off = 32; off > 0; off >>= 1) val += __shfl_down(val, off);
    if (tid == 0) atomicAdd(out, val * (1.0f / (float)N_PIX));
}

extern "C" void kernel_launch(void* const* d_in, const int* in_sizes, int n_in,
                              void* d_out, int out_size, void* d_ws, size_t ws_size,
                              hipStream_t stream) {
    const float* z1 = (const float*)d_in[0];
    const float* z2 = (const float*)d_in[1];
    float* out = (float*)d_out;

    float* ps   = (float*)d_ws;                     // 8192*32*4 = 1 MB
    float* diag = ps + (size_t)N_PIX * NSEG;        // 32 KB

    dim3 g2(N_PIX / 256, NSEG);                     // (32, 32) = 1024 blocks
    ksim<<<g2, 256, 0, stream>>>(z1, z2, ps, diag, out);
    kfinal<<<N_PIX / 64, 64, 0, stream>>>(ps, diag, out);
}

// Round 16
// 35.227 us; speedup vs baseline: 3.6400x; 3.6400x over previous
//
#include <hip/hip_runtime.h>
#include <math.h>

#define N_PIX 8192      // 2*64*64
#define D 64
#define HW 4096         // h*w
#define BSTRIDE 262144  // d*h*w
#define C1 14.4269504088896340736f   // 10 * log2(e); |dot| <= 1
#define NSEG 32
#define SEGCOLS 256
#define BC 256

typedef __attribute__((ext_vector_type(8))) short short8;   // 8 bf16 = 4 VGPR
typedef __attribute__((ext_vector_type(4))) float f32x4;

__device__ inline ushort f2bf(float x) {   // fp32 -> bf16 RNE
    uint u = __float_as_uint(x);
    return (ushort)((u + 0x7FFFu + ((u >> 16) & 1u)) >> 16);
}
__device__ inline float bflo(uint u) { return __uint_as_float(u << 16); }
__device__ inline float bfhi(uint u) { return __uint_as_float(u & 0xFFFF0000u); }

// ---------- K1: transpose + L2-normalize -> bf16 rows (N,64); 4 threads/pixel ----------
__global__ __launch_bounds__(256) void knorm(const float* __restrict__ z1,
                                             const float* __restrict__ z2,
                                             ushort* __restrict__ z1b,
                                             ushort* __restrict__ z2b,
                                             float* __restrict__ out) {
    int gid = blockIdx.x * 256 + threadIdx.x;   // 0..65535
    if (gid == 0) out[0] = 0.f;                 // fold memset (knorm precedes kfinal)
    int q = gid & 3;                             // channel quarter
    int pixg = gid >> 2;                         // 0..16383
    int t = pixg >> 13;
    int n = pixg & (N_PIX - 1);
    const float* src = t ? z2 : z1;
    ushort* dst = t ? z2b : z1b;
    int b = n >> 12;
    int p = n & 4095;
    const float* base = src + b * BSTRIDE + (q * 16) * HW + p;
    float v[16];
    float ss = 0.f;
#pragma unroll
    for (int c = 0; c < 16; ++c) { v[c] = base[c * HW]; ss += v[c] * v[c]; }
    ss += __shfl_xor(ss, 1);                     // 4-lane group shares pixel
    ss += __shfl_xor(ss, 2);
    float inv = 1.0f / fmaxf(sqrtf(ss), 1e-12f);
    uint4 w0, w1;
#pragma unroll
    for (int c2 = 0; c2 < 8; ++c2) {
        uint val = (uint)f2bf(v[2 * c2] * inv) | ((uint)f2bf(v[2 * c2 + 1] * inv) << 16);
        if (c2 < 4) ((uint*)&w0)[c2] = val; else ((uint*)&w1)[c2 - 4] = val;
    }
    uint4* o = (uint4*)(dst + (size_t)n * D + q * 16);
    o[0] = w0;
    o[1] = w1;
}

// ---------- K2: MFMA sim + fixed-shift exp; NO LDS (B is L1/L2-resident) ----------
// block = 4 waves x 64 rows = 256 rows x 256 cols; grid (32, 32) = 1024 blocks
// = 4 blocks/CU exactly. B fragments read straight from global (z2b = 1MB, L2-fits;
// 32KB panel/block fits L1). Zero barriers, zero staging instructions.
__global__ __launch_bounds__(256, 4) void ksim(const ushort* __restrict__ z1b,
                                               const ushort* __restrict__ z2b,
                                               float* __restrict__ ps) {
    int tid = threadIdx.x;
    int wave = tid >> 6, lane = tid & 63;
    int lrow = lane & 15;        // A-row / B-col within 16
    int lk = lane >> 4;          // k-chunk 0..3
    int rbase = blockIdx.x * 256 + wave * 64;
    int jbase = blockIdx.y * SEGCOLS;

    // A fragments: 4 row-tiles x 2 k-halves
    const ushort* ar = z1b + (size_t)(rbase + lrow) * D + lk * 8;
    short8 a0[4], a1[4];
#pragma unroll
    for (int rt = 0; rt < 4; ++rt) {
        a0[rt] = *(const short8*)(ar + rt * 16 * D);
        a1[rt] = *(const short8*)(ar + rt * 16 * D + 32);
    }

    float s[16];
#pragma unroll
    for (int i = 0; i < 16; ++i) s[i] = 0.f;

    const ushort* bcol = z2b + (size_t)(jbase + lrow) * D + lk * 8;
    f32x4 z = {0.f, 0.f, 0.f, 0.f};

#pragma unroll
    for (int ct = 0; ct < BC / 16; ++ct) {
        const ushort* bp = bcol + (size_t)(ct * 16) * D;
        short8 blo = *(const short8*)(bp);        // k 0..31  (lk*8 offset baked in)
        short8 bhi = *(const short8*)(bp + 32);   // k 32..63
#pragma unroll
        for (int rt = 0; rt < 4; ++rt) {
            f32x4 acc = __builtin_amdgcn_mfma_f32_16x16x32_bf16(a0[rt], blo, z, 0, 0, 0);
            acc = __builtin_amdgcn_mfma_f32_16x16x32_bf16(a1[rt], bhi, acc, 0, 0, 0);
#pragma unroll
            for (int r = 0; r < 4; ++r)
                s[rt * 4 + r] += __builtin_amdgcn_exp2f(fmaf(acc[r], C1, -C1));
        }
    }

    // reduce over 16 lanes sharing lk (different cols, same rows)
#pragma unroll
    for (int off = 1; off <= 8; off <<= 1) {
#pragma unroll
        for (int i = 0; i < 16; ++i) s[i] += __shfl_xor(s[i], off);
    }
    if (lrow == 0) {
        int seg = blockIdx.y;
#pragma unroll
        for (int rt = 0; rt < 4; ++rt)
#pragma unroll
            for (int r = 0; r < 4; ++r)
                ps[(size_t)(rbase + rt * 16 + lk * 4 + r) * NSEG + seg] = s[rt * 4 + r];
    }
}

// ---------- K3: combine partials + diag + mean via atomic ----------
__global__ __launch_bounds__(64) void kfinal(const ushort* __restrict__ z1b,
                                             const ushort* __restrict__ z2b,
                                             const float* __restrict__ ps,
                                             float* __restrict__ out) {
    int tid = threadIdx.x;
    int row = blockIdx.x * 64 + tid;

    const f32x4* pp = (const f32x4*)(ps + (size_t)row * NSEG);
    float s = 0.f;
#pragma unroll
    for (int q = 0; q < NSEG / 4; ++q) {
        f32x4 v = pp[q];
        s += (v[0] + v[1]) + (v[2] + v[3]);
    }
    const uint4* xp = (const uint4*)(z1b + (size_t)row * D);
    const uint4* yp = (const uint4*)(z2b + (size_t)row * D);
    float d = 0.f;
#pragma unroll
    for (int q = 0; q < 8; ++q) {
        uint4 x = xp[q], y = yp[q];
        d = fmaf(bflo(x.x), bflo(y.x), d); d = fmaf(bfhi(x.x), bfhi(y.x), d);
        d = fmaf(bflo(x.y), bflo(y.y), d); d = fmaf(bfhi(x.y), bfhi(y.y), d);
        d = fmaf(bflo(x.z), bflo(y.z), d); d = fmaf(bfhi(x.z), bfhi(y.z), d);
        d = fmaf(bflo(x.w), bflo(y.w), d); d = fmaf(bfhi(x.w), bfhi(y.w), d);
    }
    float val = 10.0f + __logf(s) - 10.0f * d;

#pragma unroll
    for (int off = 32; off > 0; off >>= 1) val += __shfl_down(val, off);
    if (tid == 0) atomicAdd(out, val * (1.0f / (float)N_PIX));
}

extern "C" void kernel_launch(void* const* d_in, const int* in_sizes, int n_in,
                              void* d_out, int out_size, void* d_ws, size_t ws_size,
                              hipStream_t stream) {
    const float* z1 = (const float*)d_in[0];
    const float* z2 = (const float*)d_in[1];
    float* out = (float*)d_out;

    ushort* z1b = (ushort*)d_ws;                        // 1 MB
    ushort* z2b = z1b + (size_t)N_PIX * D;              // 1 MB
    float* ps   = (float*)(z2b + (size_t)N_PIX * D);    // 8192*32*4 = 1 MB

    knorm<<<256, 256, 0, stream>>>(z1, z2, z1b, z2b, out);
    dim3 g2(N_PIX / 256, NSEG);                         // (32, 32) = 1024 blocks
    ksim<<<g2, 256, 0, stream>>>(z1b, z2b, ps);
    kfinal<<<N_PIX / 64, 64, 0, stream>>>(z1b, z2b, ps, out);
}